// Round 1
// baseline (1295.668 us; speedup 1.0000x reference)
//
#include <hip/hip_runtime.h>
#include <hip/hip_bf16.h>

#define NN 50000
#define NE 160000
#define NT 8192
#define DD 32
#define AA 6

// ---- static device scratch (avoids any dependence on ws_size) ----
__device__ float g_out[NN * DD];          // node features / GRU hidden (6.4 MB)
__device__ float g_agg[NN * DD];          // scatter accumulator (6.4 MB)
__device__ float g_invdeg[NN];            // 1/max(deg,1)
__device__ float g_h2[NE * DD];           // relu(edge_attr@nn1_w+b) (20.5 MB)
__device__ unsigned short g_wedge[(size_t)NE * 1024]; // per-edge 32x32 bf16 (327.7 MB)
__device__ float g_hl[DD], g_cl[DD], g_q[DD], g_part[DD + 1], g_pool[2 * DD];

__device__ __forceinline__ float sigm(float x) { return 1.0f / (1.0f + __expf(-x)); }
__device__ __forceinline__ float tanhx(float x) { return 1.0f - 2.0f / (__expf(2.0f * x) + 1.0f); }
__device__ __forceinline__ unsigned short f2bf(float f) {
    unsigned int u = __float_as_uint(f);
    u = (u + 0x7fffu + ((u >> 16) & 1u)) >> 16;
    return (unsigned short)u;
}
__device__ __forceinline__ float bflo(unsigned int pk) { return __uint_as_float(pk << 16); }
__device__ __forceinline__ float bfhi(unsigned int pk) { return __uint_as_float(pk & 0xffff0000u); }
__device__ __forceinline__ void fma4(float4& a, float s, const float4 b) {
    a.x = fmaf(s, b.x, a.x); a.y = fmaf(s, b.y, a.y);
    a.z = fmaf(s, b.z, a.z); a.w = fmaf(s, b.w, a.w);
}

// out = relu(x @ lin0_w + lin0_b); zero agg; zero deg counter
__global__ __launch_bounds__(256) void k_init(const float* __restrict__ x,
                                              const float* __restrict__ w,
                                              const float* __restrict__ b) {
    const int t = blockIdx.x * 256 + threadIdx.x;   // exact N*32
    const int n = t >> 5, d = t & 31;
    float v = b[d];
    v = fmaf(x[n * 3 + 0], w[0 * DD + d], v);
    v = fmaf(x[n * 3 + 1], w[1 * DD + d], v);
    v = fmaf(x[n * 3 + 2], w[2 * DD + d], v);
    g_out[t] = fmaxf(v, 0.f);
    g_agg[t] = 0.f;
    if (d == 0) g_invdeg[n] = 0.f;
}

__global__ __launch_bounds__(256) void k_deg(const int* __restrict__ ei) {
    const int e = blockIdx.x * 256 + threadIdx.x;   // exact E
    atomicAdd(&g_invdeg[ei[NE + e]], 1.0f);
}

__global__ __launch_bounds__(256) void k_invdeg() {
    const int n = blockIdx.x * 256 + threadIdx.x;
    if (n < NN) g_invdeg[n] = 1.0f / fmaxf(g_invdeg[n], 1.0f);
}

// h2 = relu(edge_attr @ nn1_w + nn1_b)
__global__ __launch_bounds__(256) void k_h2(const float* __restrict__ ea,
                                            const float* __restrict__ w,
                                            const float* __restrict__ b) {
    const int t = blockIdx.x * 256 + threadIdx.x;   // exact E*32
    const int e = t >> 5, k = t & 31;
    float acc = b[k];
#pragma unroll
    for (int i = 0; i < 7; ++i) acc = fmaf(ea[e * 7 + i], w[i * DD + k], acc);
    g_h2[t] = fmaxf(acc, 0.f);
}

// Wedge[e, i*32+o] = bf16( h2[e,:] @ nn2_w[:, i*32+o] + nn2_b )
// thread owns a j-quad (4 columns of W2 held in 128 VGPRs), loops over edges.
__global__ __launch_bounds__(256, 1) void k_wedge(const float* __restrict__ w2m,
                                                  const float* __restrict__ b2m) {
    __shared__ float sh2[64 * DD];
    const int j0 = threadIdx.x * 4;
    float4 w[DD];
#pragma unroll
    for (int k = 0; k < DD; ++k) w[k] = *(const float4*)&w2m[k * 1024 + j0];
    const float4 bb = *(const float4*)&b2m[j0];
    const int nChunk = NE / 64;  // 2500
    for (int c = blockIdx.x; c < nChunk; c += gridDim.x) {
        const int e0 = c * 64;
        __syncthreads();
        const float4* srcp = (const float4*)&g_h2[e0 * DD];
        float4* dstp = (float4*)sh2;
        dstp[threadIdx.x] = srcp[threadIdx.x];
        dstp[256 + threadIdx.x] = srcp[256 + threadIdx.x];
        __syncthreads();
        for (int el = 0; el < 64; ++el) {
            float4 acc = bb;
#pragma unroll
            for (int k4 = 0; k4 < 8; ++k4) {
                const float4 h4 = *(const float4*)&sh2[el * DD + k4 * 4];
                fma4(acc, h4.x, w[k4 * 4 + 0]);
                fma4(acc, h4.y, w[k4 * 4 + 1]);
                fma4(acc, h4.z, w[k4 * 4 + 2]);
                fma4(acc, h4.w, w[k4 * 4 + 3]);
            }
            uint2 pk;
            pk.x = (unsigned int)f2bf(acc.x) | ((unsigned int)f2bf(acc.y) << 16);
            pk.y = (unsigned int)f2bf(acc.z) | ((unsigned int)f2bf(acc.w) << 16);
            *(uint2*)&g_wedge[(size_t)(e0 + el) * 1024 + j0] = pk;
        }
    }
}

// msg[e,o] = sum_i out[src,i] * Wedge[e,i,o]; atomicAdd into agg[dst,o]
// 16 lanes per edge, 2 outputs per lane; u broadcast via shfl.
__global__ __launch_bounds__(256) void k_edge(const int* __restrict__ ei) {
    const int t = blockIdx.x * 256 + threadIdx.x;  // exact E*16
    const int e = t >> 4, op = t & 15;
    const int src = ei[e], dst = ei[NE + e];
    const float2 u2 = *(const float2*)&g_out[src * DD + 2 * op];
    const unsigned int* wp = (const unsigned int*)g_wedge + (size_t)e * 512 + op;
    const int lane = threadIdx.x & 63;
    const int gb = lane & 48;
    float a0 = 0.f, a1 = 0.f;
#pragma unroll
    for (int i = 0; i < 32; ++i) {
        const float ui = __shfl((i & 1) ? u2.y : u2.x, gb | (i >> 1), 64);
        const unsigned int pk = wp[i * 16];
        a0 = fmaf(ui, bflo(pk), a0);
        a1 = fmaf(ui, bfhi(pk), a1);
    }
    atomicAdd(&g_agg[dst * DD + 2 * op], a0);
    atomicAdd(&g_agg[dst * DD + 2 * op + 1], a1);
}

// m = relu(out@root + agg/deg + cb); GRU update; re-zero agg
__global__ __launch_bounds__(256) void k_node(const float* __restrict__ root,
                                              const float* __restrict__ cb,
                                              const float* __restrict__ wih,
                                              const float* __restrict__ whh,
                                              const float* __restrict__ bih,
                                              const float* __restrict__ bhh) {
    __shared__ float s_root[1024];
    __shared__ float s_wih[3072];
    __shared__ float s_whh[3072];
    __shared__ float s_bih[96], s_bhh[96], s_cb[DD];
    for (int i = threadIdx.x; i < 1024; i += 256) s_root[i] = root[i];
    for (int i = threadIdx.x; i < 3072; i += 256) s_wih[i] = wih[i];
    for (int i = threadIdx.x; i < 3072; i += 256) s_whh[i] = whh[i];
    if (threadIdx.x < 96) { s_bih[threadIdx.x] = bih[threadIdx.x]; s_bhh[threadIdx.x] = bhh[threadIdx.x]; }
    if (threadIdx.x >= 96 && threadIdx.x < 128) s_cb[threadIdx.x - 96] = cb[threadIdx.x - 96];
    __syncthreads();
    const int n = blockIdx.x * 256 + threadIdx.x;
    if (n >= NN) return;
    float h[DD], m[DD], rr[DD], zz[DD];
    const float inv = g_invdeg[n];
#pragma unroll
    for (int q = 0; q < 8; ++q) *(float4*)&h[4 * q] = *(const float4*)&g_out[n * DD + 4 * q];
#pragma unroll
    for (int q = 0; q < 8; ++q) {
        float4 a = *(const float4*)&g_agg[n * DD + 4 * q];
        const float4 c = *(const float4*)&s_cb[4 * q];
        a.x = fmaf(a.x, inv, c.x); a.y = fmaf(a.y, inv, c.y);
        a.z = fmaf(a.z, inv, c.z); a.w = fmaf(a.w, inv, c.w);
#pragma unroll
        for (int i = 0; i < DD; ++i) fma4(a, h[i], *(const float4*)&s_root[i * DD + 4 * q]);
        m[4 * q + 0] = fmaxf(a.x, 0.f); m[4 * q + 1] = fmaxf(a.y, 0.f);
        m[4 * q + 2] = fmaxf(a.z, 0.f); m[4 * q + 3] = fmaxf(a.w, 0.f);
        *(float4*)&g_agg[n * DD + 4 * q] = make_float4(0.f, 0.f, 0.f, 0.f);  // ready for next iter
    }
    // r gate (offset 0)
#pragma unroll
    for (int q = 0; q < 8; ++q) {
        float4 a = *(const float4*)&s_bih[4 * q];
        const float4 b = *(const float4*)&s_bhh[4 * q];
        a.x += b.x; a.y += b.y; a.z += b.z; a.w += b.w;
#pragma unroll
        for (int i = 0; i < DD; ++i) {
            fma4(a, m[i], *(const float4*)&s_wih[i * 96 + 4 * q]);
            fma4(a, h[i], *(const float4*)&s_whh[i * 96 + 4 * q]);
        }
        rr[4 * q + 0] = sigm(a.x); rr[4 * q + 1] = sigm(a.y);
        rr[4 * q + 2] = sigm(a.z); rr[4 * q + 3] = sigm(a.w);
    }
    // z gate (offset 32)
#pragma unroll
    for (int q = 0; q < 8; ++q) {
        float4 a = *(const float4*)&s_bih[32 + 4 * q];
        const float4 b = *(const float4*)&s_bhh[32 + 4 * q];
        a.x += b.x; a.y += b.y; a.z += b.z; a.w += b.w;
#pragma unroll
        for (int i = 0; i < DD; ++i) {
            fma4(a, m[i], *(const float4*)&s_wih[i * 96 + 32 + 4 * q]);
            fma4(a, h[i], *(const float4*)&s_whh[i * 96 + 32 + 4 * q]);
        }
        zz[4 * q + 0] = sigm(a.x); zz[4 * q + 1] = sigm(a.y);
        zz[4 * q + 2] = sigm(a.z); zz[4 * q + 3] = sigm(a.w);
    }
    // n gate (offset 64) + hidden update
#pragma unroll
    for (int q = 0; q < 8; ++q) {
        float4 gx = *(const float4*)&s_bih[64 + 4 * q];
        float4 gh = *(const float4*)&s_bhh[64 + 4 * q];
#pragma unroll
        for (int i = 0; i < DD; ++i) {
            fma4(gx, m[i], *(const float4*)&s_wih[i * 96 + 64 + 4 * q]);
            fma4(gh, h[i], *(const float4*)&s_whh[i * 96 + 64 + 4 * q]);
        }
        float4 hn;
        { const float nv = tanhx(gx.x + rr[4 * q + 0] * gh.x); hn.x = (1.f - zz[4 * q + 0]) * nv + zz[4 * q + 0] * h[4 * q + 0]; }
        { const float nv = tanhx(gx.y + rr[4 * q + 1] * gh.y); hn.y = (1.f - zz[4 * q + 1]) * nv + zz[4 * q + 1] * h[4 * q + 1]; }
        { const float nv = tanhx(gx.z + rr[4 * q + 2] * gh.z); hn.z = (1.f - zz[4 * q + 2]) * nv + zz[4 * q + 2] * h[4 * q + 2]; }
        { const float nv = tanhx(gx.w + rr[4 * q + 3] * gh.w); hn.w = (1.f - zz[4 * q + 3]) * nv + zz[4 * q + 3] * h[4 * q + 3]; }
        *(float4*)&g_out[n * DD + 4 * q] = hn;
    }
}

// Set2Set LSTM step (1 block, 128 threads). step>0: finalize r from attention partials.
__global__ void k_lstm(const float* __restrict__ wih, const float* __restrict__ whh,
                       const float* __restrict__ bih, const float* __restrict__ bhh,
                       const int step) {
    __shared__ float qs[64];
    __shared__ float shl[DD];
    __shared__ float g[128];
    const int t = threadIdx.x;
    if (step == 0) {
        if (t < 64) qs[t] = 0.f;
        if (t < DD) shl[t] = 0.f;
    } else {
        if (t < DD) { qs[t] = g_q[t]; shl[t] = g_hl[t]; }
        else if (t < 64) qs[t] = g_part[1 + (t - DD)] / g_part[0];
    }
    __syncthreads();
    if (t >= 64 && t < 97) g_part[t - 64] = 0.f;  // zero partials for upcoming attention
    float acc = bih[t] + bhh[t];
    for (int i = 0; i < 64; ++i) acc = fmaf(qs[i], wih[i * 128 + t], acc);
    for (int i = 0; i < DD; ++i) acc = fmaf(shl[i], whh[i * 128 + t], acc);
    g[t] = acc;
    __syncthreads();
    if (t < DD) {
        const float ig = sigm(g[t]);
        const float fg = sigm(g[DD + t]);
        const float gg = tanhx(g[2 * DD + t]);
        const float og = sigm(g[3 * DD + t]);
        float c = (step == 0) ? 0.f : g_cl[t];
        c = fmaf(fg, c, ig * gg);
        const float hn = og * tanhx(c);
        g_cl[t] = c; g_hl[t] = hn; g_q[t] = hn;
    }
}

// attention pass: partial sum(exp(out.q)) and sum(exp * out) -> g_part via atomics
__global__ __launch_bounds__(256) void k_att() {
    __shared__ float sq[DD];
    __shared__ float red[4][DD + 1];
    if (threadIdx.x < DD) sq[threadIdx.x] = g_q[threadIdx.x];
    __syncthreads();
    float pe = 0.f;
    float pv[DD];
#pragma unroll
    for (int i = 0; i < DD; ++i) pv[i] = 0.f;
    for (int n = blockIdx.x * blockDim.x + threadIdx.x; n < NN; n += gridDim.x * blockDim.x) {
        float row[DD];
#pragma unroll
        for (int q = 0; q < 8; ++q) *(float4*)&row[4 * q] = *(const float4*)&g_out[n * DD + 4 * q];
        float dot = 0.f;
#pragma unroll
        for (int i = 0; i < DD; ++i) dot = fmaf(row[i], sq[i], dot);
        const float e = __expf(dot);   // |dot| <= 32, safe
        pe += e;
#pragma unroll
        for (int i = 0; i < DD; ++i) pv[i] = fmaf(e, row[i], pv[i]);
    }
#pragma unroll
    for (int off = 32; off > 0; off >>= 1) {
        pe += __shfl_down(pe, off, 64);
#pragma unroll
        for (int i = 0; i < DD; ++i) pv[i] += __shfl_down(pv[i], off, 64);
    }
    const int wid = threadIdx.x >> 6, lane = threadIdx.x & 63;
    if (lane == 0) {
        red[wid][0] = pe;
#pragma unroll
        for (int i = 0; i < DD; ++i) red[wid][1 + i] = pv[i];
    }
    __syncthreads();
    if (threadIdx.x < DD + 1) {
        const float s = red[0][threadIdx.x] + red[1][threadIdx.x] + red[2][threadIdx.x] + red[3][threadIdx.x];
        atomicAdd(&g_part[threadIdx.x], s);
    }
}

__global__ void k_pool() {
    const int t = threadIdx.x;  // 64
    if (t < DD) g_pool[t] = g_q[t];
    else g_pool[t] = g_part[1 + (t - DD)] / g_part[0];
}

// readout: y = relu(cat @ lin1 + b1) @ lin2 + b2 with the faithful reshape semantics
__global__ __launch_bounds__(256) void k_readout(const int* __restrict__ nr,
                                                 const float* __restrict__ w1,
                                                 const float* __restrict__ b1,
                                                 const float* __restrict__ w2,
                                                 const float* __restrict__ b2,
                                                 float* __restrict__ yout) {
    __shared__ float sw1[192 * DD];
    __shared__ float sS1[DD];
    __shared__ float sw2[DD * AA];
    __shared__ float sb1[DD];
    __shared__ float sb2[AA];
    for (int i = threadIdx.x; i < 192 * DD; i += 256) sw1[i] = w1[i];
    for (int i = threadIdx.x; i < DD * AA; i += 256) sw2[i] = w2[i];
    if (threadIdx.x < DD) sb1[threadIdx.x] = b1[threadIdx.x];
    if (threadIdx.x < AA) sb2[threadIdx.x] = b2[threadIdx.x];
    __syncthreads();
    if (threadIdx.x < DD) {
        float s = 0.f;
        for (int c = 0; c < 64; ++c) s += sw1[(128 + c) * DD + threadIdx.x];
        sS1[threadIdx.x] = s;
    }
    __syncthreads();
    const int lane = threadIdx.x & 31;
    const int grp = (blockIdx.x * 256 + threadIdx.x) >> 5;  // 0..255
    const int t0 = grp * 32;
    const int t = t0 + lane;
    const float poolv = g_pool[t0 >> 7];
    const int col = (t0 >> 5) & 3;
    const int rowbase = t0 >> 7;
    float4 acc[8];
#pragma unroll
    for (int q = 0; q < 8; ++q) {
        acc[q].x = fmaf(poolv, sS1[4 * q + 0], sb1[4 * q + 0]);
        acc[q].y = fmaf(poolv, sS1[4 * q + 1], sb1[4 * q + 1]);
        acc[q].z = fmaf(poolv, sS1[4 * q + 2], sb1[4 * q + 2]);
        acc[q].w = fmaf(poolv, sS1[4 * q + 3], sb1[4 * q + 3]);
    }
    for (int p = 0; p < 128; ++p) {
        const int node = nr[(p * 64 + rowbase) * 4 + col];
        const float v = g_out[node * DD + lane];
#pragma unroll
        for (int q = 0; q < 8; ++q) fma4(acc[q], v, *(const float4*)&sw1[p * DD + 4 * q]);
    }
    float y[AA];
#pragma unroll
    for (int a = 0; a < AA; ++a) y[a] = sb2[a];
#pragma unroll
    for (int q = 0; q < 8; ++q) {
        const float vals[4] = {acc[q].x, acc[q].y, acc[q].z, acc[q].w};
#pragma unroll
        for (int c = 0; c < 4; ++c) {
            const float ad = fmaxf(vals[c], 0.f);
            const int d = 4 * q + c;
#pragma unroll
            for (int a = 0; a < AA; ++a) y[a] = fmaf(ad, sw2[d * AA + a], y[a]);
        }
    }
#pragma unroll
    for (int a = 0; a < AA; ++a) yout[t * AA + a] = y[a];
}

extern "C" void kernel_launch(void* const* d_in, const int* in_sizes, int n_in,
                              void* d_out, int out_size, void* d_ws, size_t ws_size,
                              hipStream_t stream) {
    (void)in_sizes; (void)n_in; (void)out_size; (void)d_ws; (void)ws_size;
    const float* x        = (const float*)d_in[0];
    const int*   ei       = (const int*)d_in[1];
    const float* ea       = (const float*)d_in[2];
    const int*   nonring  = (const int*)d_in[3];
    const float* lin0_w   = (const float*)d_in[4];
    const float* lin0_b   = (const float*)d_in[5];
    const float* nn1_w    = (const float*)d_in[6];
    const float* nn1_b    = (const float*)d_in[7];
    const float* nn2_w    = (const float*)d_in[8];
    const float* nn2_b    = (const float*)d_in[9];
    const float* conv_root= (const float*)d_in[10];
    const float* conv_b   = (const float*)d_in[11];
    const float* gru_w_ih = (const float*)d_in[12];
    const float* gru_w_hh = (const float*)d_in[13];
    const float* gru_b_ih = (const float*)d_in[14];
    const float* gru_b_hh = (const float*)d_in[15];
    const float* lstm_w_ih= (const float*)d_in[16];
    const float* lstm_w_hh= (const float*)d_in[17];
    const float* lstm_b_ih= (const float*)d_in[18];
    const float* lstm_b_hh= (const float*)d_in[19];
    const float* lin1_w   = (const float*)d_in[20];
    const float* lin1_b   = (const float*)d_in[21];
    const float* lin2_w   = (const float*)d_in[22];
    const float* lin2_b   = (const float*)d_in[23];
    float* out = (float*)d_out;

    k_init<<<(NN * DD) / 256, 256, 0, stream>>>(x, lin0_w, lin0_b);
    k_deg<<<NE / 256, 256, 0, stream>>>(ei);
    k_invdeg<<<(NN + 255) / 256, 256, 0, stream>>>();
    k_h2<<<(NE * DD) / 256, 256, 0, stream>>>(ea, nn1_w, nn1_b);
    k_wedge<<<320, 256, 0, stream>>>(nn2_w, nn2_b);
    for (int it = 0; it < 6; ++it) {
        k_edge<<<(NE * 16) / 256, 256, 0, stream>>>(ei);
        k_node<<<(NN + 255) / 256, 256, 0, stream>>>(conv_root, conv_b, gru_w_ih, gru_w_hh,
                                                     gru_b_ih, gru_b_hh);
    }
    for (int s = 0; s < 6; ++s) {
        k_lstm<<<1, 128, 0, stream>>>(lstm_w_ih, lstm_w_hh, lstm_b_ih, lstm_b_hh, s);
        k_att<<<128, 256, 0, stream>>>();
    }
    k_pool<<<1, 64, 0, stream>>>();
    k_readout<<<32, 256, 0, stream>>>(nonring, lin1_w, lin1_b, lin2_w, lin2_b, out);
}

// Round 2
// 722.403 us; speedup vs baseline: 1.7936x; 1.7936x over previous
//
#include <hip/hip_runtime.h>
#include <hip/hip_bf16.h>

#define NN 50000
#define NE 160000
#define NT 8192
#define DD 32
#define AA 6

typedef __attribute__((ext_vector_type(8))) short bf16x8s;
typedef __attribute__((ext_vector_type(4))) float f32x4;

// ---- static device scratch ----
__device__ float g_out[NN * DD];          // node features / GRU hidden (6.4 MB)
__device__ float g_agg[NN * DD];          // scatter accumulator (6.4 MB)
__device__ float g_invdeg[NN];            // raw in-degree count (inverted in k_node)
__device__ float g_h2[NE * DD];           // relu(edge_attr@nn1_w+b) (20.5 MB)
__device__ bf16x8s g_w2frag[33 * 2 * 64]; // prepacked B fragments (66 KB)
__device__ float g_hl[DD], g_cl[DD], g_q[DD], g_part[DD + 1];

__device__ __forceinline__ float sigm(float x) { return 1.0f / (1.0f + __expf(-x)); }
__device__ __forceinline__ float tanhx(float x) { return 1.0f - 2.0f / (__expf(2.0f * x) + 1.0f); }
__device__ __forceinline__ unsigned short f2bf(float f) {
    unsigned int u = __float_as_uint(f);
    u = (u + 0x7fffu + ((u >> 16) & 1u)) >> 16;
    return (unsigned short)u;
}
__device__ __forceinline__ void fma4(float4& a, float s, const float4 b) {
    a.x = fmaf(s, b.x, a.x); a.y = fmaf(s, b.y, a.y);
    a.z = fmaf(s, b.z, a.z); a.w = fmaf(s, b.w, a.w);
}
#define CVTPK(dst, lo, hi) asm("v_cvt_pk_bf16_f32 %0, %1, %2" : "=v"(dst) : "v"(lo), "v"(hi))

// out = relu(x @ lin0_w + lin0_b); zero agg; zero deg counter
__global__ __launch_bounds__(256) void k_init(const float* __restrict__ x,
                                              const float* __restrict__ w,
                                              const float* __restrict__ b) {
    const int t = blockIdx.x * 256 + threadIdx.x;   // exact N*32
    const int n = t >> 5, d = t & 31;
    float v = b[d];
    v = fmaf(x[n * 3 + 0], w[0 * DD + d], v);
    v = fmaf(x[n * 3 + 1], w[1 * DD + d], v);
    v = fmaf(x[n * 3 + 2], w[2 * DD + d], v);
    g_out[t] = fmaxf(v, 0.f);
    g_agg[t] = 0.f;
    if (d == 0) g_invdeg[n] = 0.f;
}

__global__ __launch_bounds__(256) void k_deg(const int* __restrict__ ei) {
    const int e = blockIdx.x * 256 + threadIdx.x;   // exact E
    atomicAdd(&g_invdeg[ei[NE + e]], 1.0f);
}

// h2 = relu(edge_attr @ nn1_w + nn1_b)
__global__ __launch_bounds__(256) void k_h2(const float* __restrict__ ea,
                                            const float* __restrict__ w,
                                            const float* __restrict__ b) {
    const int t = blockIdx.x * 256 + threadIdx.x;   // exact E*32
    const int e = t >> 5, k = t & 31;
    float acc = b[k];
#pragma unroll
    for (int i = 0; i < 7; ++i) acc = fmaf(ea[e * 7 + i], w[i * DD + k], acc);
    g_h2[t] = fmaxf(acc, 0.f);
}

// Prepack B fragments: frag[s][c][lane][j] = bf16( W2'[32s + 8*(lane>>4) + j][c*16 + (lane&15)] )
// W2' is nn2_w viewed as [1024][32]; step s==32 holds the nn2_b bias rows.
__global__ __launch_bounds__(256) void k_w2frag(const float* __restrict__ w2m,
                                                const float* __restrict__ b2m) {
    const int idx = blockIdx.x * 256 + threadIdx.x;  // exact 33*2*64*8 = 33792
    const int j = idx & 7, l = (idx >> 3) & 63, c = (idx >> 9) & 1, s = idx >> 10;
    const int kk = (l >> 4) * 8 + j;
    const int col = c * 16 + (l & 15);
    const float v = (s == 32) ? b2m[kk * DD + col] : w2m[(32 * s + kk) * DD + col];
    ((unsigned short*)g_w2frag)[idx] = f2bf(v);
}

// Fused NNConv edge pass via MFMA: msg = z @ W2' with z = h2 (x) u built in registers.
// One wave per 16-edge group; 2 col-tiles of 16 outputs; 33 K-steps (last = bias).
__global__ __launch_bounds__(512) void k_edge_mfma(const int* __restrict__ ei) {
    __shared__ bf16x8s sB[33 * 2 * 64];   // 66 KB
    for (int i = threadIdx.x; i < 33 * 2 * 64; i += 512)
        ((uint4*)sB)[i] = ((const uint4*)g_w2frag)[i];
    __syncthreads();

    const int wid = threadIdx.x >> 6, lane = threadIdx.x & 63;
    const int g = blockIdx.x * 8 + wid;              // exact: 1250*8 = 10000 = NE/16
    const int e0 = g * 16;
    const int egrp = lane & 15;                      // A-fragment row (edge in group)
    const int quad = lane >> 4;                      // k-subgroup
    const int e = e0 + egrp;
    const int src = ei[e];

    const float4 u0 = *(const float4*)&g_out[src * DD + quad * 8];
    const float4 u1 = *(const float4*)&g_out[src * DD + quad * 8 + 4];
    float h2r[DD];
#pragma unroll
    for (int q = 0; q < 8; ++q)
        *(float4*)&h2r[4 * q] = *(const float4*)&g_h2[(size_t)e * DD + 4 * q];

    union ABu { bf16x8s v; unsigned int u[4]; };
    ABu Au;                                          // bias-step A = bf16(u)
    CVTPK(Au.u[0], u0.x, u0.y); CVTPK(Au.u[1], u0.z, u0.w);
    CVTPK(Au.u[2], u1.x, u1.y); CVTPK(Au.u[3], u1.z, u1.w);

    f32x4 acc0 = {0.f, 0.f, 0.f, 0.f};
    f32x4 acc1 = {0.f, 0.f, 0.f, 0.f};
#pragma unroll
    for (int s = 0; s < DD; ++s) {
        const float hs = h2r[s];
        ABu A;
        CVTPK(A.u[0], hs * u0.x, hs * u0.y);
        CVTPK(A.u[1], hs * u0.z, hs * u0.w);
        CVTPK(A.u[2], hs * u1.x, hs * u1.y);
        CVTPK(A.u[3], hs * u1.z, hs * u1.w);
        const bf16x8s b0 = sB[s * 128 + lane];
        const bf16x8s b1 = sB[s * 128 + 64 + lane];
        acc0 = __builtin_amdgcn_mfma_f32_16x16x32_bf16(A.v, b0, acc0, 0, 0, 0);
        acc1 = __builtin_amdgcn_mfma_f32_16x16x32_bf16(A.v, b1, acc1, 0, 0, 0);
    }
    {   // bias step (k = 1024..1055): A = u, B = nn2_b fragments
        const bf16x8s b0 = sB[32 * 128 + lane];
        const bf16x8s b1 = sB[32 * 128 + 64 + lane];
        acc0 = __builtin_amdgcn_mfma_f32_16x16x32_bf16(Au.v, b0, acc0, 0, 0, 0);
        acc1 = __builtin_amdgcn_mfma_f32_16x16x32_bf16(Au.v, b1, acc1, 0, 0, 0);
    }
    // D layout: row (edge) = quad*4 + r, col (output) = lane&15  [m89-verified]
    const int oc = lane & 15;
#pragma unroll
    for (int r = 0; r < 4; ++r) {
        const int dstn = ei[NE + e0 + quad * 4 + r];
        atomicAdd(&g_agg[dstn * DD + oc], acc0[r]);
        atomicAdd(&g_agg[dstn * DD + 16 + oc], acc1[r]);
    }
}

// m = relu(out@root + agg/deg + cb); GRU update; re-zero agg
__global__ __launch_bounds__(256) void k_node(const float* __restrict__ root,
                                              const float* __restrict__ cb,
                                              const float* __restrict__ wih,
                                              const float* __restrict__ whh,
                                              const float* __restrict__ bih,
                                              const float* __restrict__ bhh) {
    __shared__ float s_root[1024];
    __shared__ float s_wih[3072];
    __shared__ float s_whh[3072];
    __shared__ float s_bih[96], s_bhh[96], s_cb[DD];
    for (int i = threadIdx.x; i < 1024; i += 256) s_root[i] = root[i];
    for (int i = threadIdx.x; i < 3072; i += 256) s_wih[i] = wih[i];
    for (int i = threadIdx.x; i < 3072; i += 256) s_whh[i] = whh[i];
    if (threadIdx.x < 96) { s_bih[threadIdx.x] = bih[threadIdx.x]; s_bhh[threadIdx.x] = bhh[threadIdx.x]; }
    if (threadIdx.x >= 96 && threadIdx.x < 128) s_cb[threadIdx.x - 96] = cb[threadIdx.x - 96];
    __syncthreads();
    const int n = blockIdx.x * 256 + threadIdx.x;
    if (n >= NN) return;
    float h[DD], m[DD], rr[DD], zz[DD];
    const float inv = 1.0f / fmaxf(g_invdeg[n], 1.0f);
#pragma unroll
    for (int q = 0; q < 8; ++q) *(float4*)&h[4 * q] = *(const float4*)&g_out[n * DD + 4 * q];
#pragma unroll
    for (int q = 0; q < 8; ++q) {
        float4 a = *(const float4*)&g_agg[n * DD + 4 * q];
        const float4 c = *(const float4*)&s_cb[4 * q];
        a.x = fmaf(a.x, inv, c.x); a.y = fmaf(a.y, inv, c.y);
        a.z = fmaf(a.z, inv, c.z); a.w = fmaf(a.w, inv, c.w);
#pragma unroll
        for (int i = 0; i < DD; ++i) fma4(a, h[i], *(const float4*)&s_root[i * DD + 4 * q]);
        m[4 * q + 0] = fmaxf(a.x, 0.f); m[4 * q + 1] = fmaxf(a.y, 0.f);
        m[4 * q + 2] = fmaxf(a.z, 0.f); m[4 * q + 3] = fmaxf(a.w, 0.f);
        *(float4*)&g_agg[n * DD + 4 * q] = make_float4(0.f, 0.f, 0.f, 0.f);  // ready for next iter
    }
#pragma unroll
    for (int q = 0; q < 8; ++q) {
        float4 a = *(const float4*)&s_bih[4 * q];
        const float4 b = *(const float4*)&s_bhh[4 * q];
        a.x += b.x; a.y += b.y; a.z += b.z; a.w += b.w;
#pragma unroll
        for (int i = 0; i < DD; ++i) {
            fma4(a, m[i], *(const float4*)&s_wih[i * 96 + 4 * q]);
            fma4(a, h[i], *(const float4*)&s_whh[i * 96 + 4 * q]);
        }
        rr[4 * q + 0] = sigm(a.x); rr[4 * q + 1] = sigm(a.y);
        rr[4 * q + 2] = sigm(a.z); rr[4 * q + 3] = sigm(a.w);
    }
#pragma unroll
    for (int q = 0; q < 8; ++q) {
        float4 a = *(const float4*)&s_bih[32 + 4 * q];
        const float4 b = *(const float4*)&s_bhh[32 + 4 * q];
        a.x += b.x; a.y += b.y; a.z += b.z; a.w += b.w;
#pragma unroll
        for (int i = 0; i < DD; ++i) {
            fma4(a, m[i], *(const float4*)&s_wih[i * 96 + 32 + 4 * q]);
            fma4(a, h[i], *(const float4*)&s_whh[i * 96 + 32 + 4 * q]);
        }
        zz[4 * q + 0] = sigm(a.x); zz[4 * q + 1] = sigm(a.y);
        zz[4 * q + 2] = sigm(a.z); zz[4 * q + 3] = sigm(a.w);
    }
#pragma unroll
    for (int q = 0; q < 8; ++q) {
        float4 gx = *(const float4*)&s_bih[64 + 4 * q];
        float4 gh = *(const float4*)&s_bhh[64 + 4 * q];
#pragma unroll
        for (int i = 0; i < DD; ++i) {
            fma4(gx, m[i], *(const float4*)&s_wih[i * 96 + 64 + 4 * q]);
            fma4(gh, h[i], *(const float4*)&s_whh[i * 96 + 64 + 4 * q]);
        }
        float4 hn;
        { const float nv = tanhx(gx.x + rr[4 * q + 0] * gh.x); hn.x = (1.f - zz[4 * q + 0]) * nv + zz[4 * q + 0] * h[4 * q + 0]; }
        { const float nv = tanhx(gx.y + rr[4 * q + 1] * gh.y); hn.y = (1.f - zz[4 * q + 1]) * nv + zz[4 * q + 1] * h[4 * q + 1]; }
        { const float nv = tanhx(gx.z + rr[4 * q + 2] * gh.z); hn.z = (1.f - zz[4 * q + 2]) * nv + zz[4 * q + 2] * h[4 * q + 2]; }
        { const float nv = tanhx(gx.w + rr[4 * q + 3] * gh.w); hn.w = (1.f - zz[4 * q + 3]) * nv + zz[4 * q + 3] * h[4 * q + 3]; }
        *(float4*)&g_out[n * DD + 4 * q] = hn;
    }
}

// Set2Set LSTM step (1 block, 128 threads). step>0: finalize r from attention partials.
__global__ void k_lstm(const float* __restrict__ wih, const float* __restrict__ whh,
                       const float* __restrict__ bih, const float* __restrict__ bhh,
                       const int step) {
    __shared__ float qs[64];
    __shared__ float shl[DD];
    __shared__ float g[128];
    const int t = threadIdx.x;
    if (step == 0) {
        if (t < 64) qs[t] = 0.f;
        if (t < DD) shl[t] = 0.f;
    } else {
        if (t < DD) { qs[t] = g_q[t]; shl[t] = g_hl[t]; }
        else if (t < 64) qs[t] = g_part[1 + (t - DD)] / g_part[0];
    }
    __syncthreads();
    if (t >= 64 && t < 97) g_part[t - 64] = 0.f;  // zero partials for upcoming attention
    float acc = bih[t] + bhh[t];
    for (int i = 0; i < 64; ++i) acc = fmaf(qs[i], wih[i * 128 + t], acc);
    for (int i = 0; i < DD; ++i) acc = fmaf(shl[i], whh[i * 128 + t], acc);
    g[t] = acc;
    __syncthreads();
    if (t < DD) {
        const float ig = sigm(g[t]);
        const float fg = sigm(g[DD + t]);
        const float gg = tanhx(g[2 * DD + t]);
        const float og = sigm(g[3 * DD + t]);
        float c = (step == 0) ? 0.f : g_cl[t];
        c = fmaf(fg, c, ig * gg);
        const float hn = og * tanhx(c);
        g_cl[t] = c; g_hl[t] = hn; g_q[t] = hn;
    }
}

// attention pass: partial sum(exp(out.q)) and sum(exp * out) -> g_part via atomics
__global__ __launch_bounds__(256) void k_att() {
    __shared__ float sq[DD];
    __shared__ float red[4][DD + 1];
    if (threadIdx.x < DD) sq[threadIdx.x] = g_q[threadIdx.x];
    __syncthreads();
    float pe = 0.f;
    float pv[DD];
#pragma unroll
    for (int i = 0; i < DD; ++i) pv[i] = 0.f;
    for (int n = blockIdx.x * blockDim.x + threadIdx.x; n < NN; n += gridDim.x * blockDim.x) {
        float row[DD];
#pragma unroll
        for (int q = 0; q < 8; ++q) *(float4*)&row[4 * q] = *(const float4*)&g_out[n * DD + 4 * q];
        float dot = 0.f;
#pragma unroll
        for (int i = 0; i < DD; ++i) dot = fmaf(row[i], sq[i], dot);
        const float e = __expf(dot);
        pe += e;
#pragma unroll
        for (int i = 0; i < DD; ++i) pv[i] = fmaf(e, row[i], pv[i]);
    }
#pragma unroll
    for (int off = 32; off > 0; off >>= 1) {
        pe += __shfl_down(pe, off, 64);
#pragma unroll
        for (int i = 0; i < DD; ++i) pv[i] += __shfl_down(pv[i], off, 64);
    }
    const int wid = threadIdx.x >> 6, lane = threadIdx.x & 63;
    if (lane == 0) {
        red[wid][0] = pe;
#pragma unroll
        for (int i = 0; i < DD; ++i) red[wid][1 + i] = pv[i];
    }
    __syncthreads();
    if (threadIdx.x < DD + 1) {
        const float s = red[0][threadIdx.x] + red[1][threadIdx.x] + red[2][threadIdx.x] + red[3][threadIdx.x];
        atomicAdd(&g_part[threadIdx.x], s);
    }
}

// readout: y = relu(cat @ lin1 + b1) @ lin2 + b2 with the faithful reshape semantics
__global__ __launch_bounds__(256) void k_readout(const int* __restrict__ nr,
                                                 const float* __restrict__ w1,
                                                 const float* __restrict__ b1,
                                                 const float* __restrict__ w2,
                                                 const float* __restrict__ b2,
                                                 float* __restrict__ yout) {
    __shared__ float sw1[192 * DD];
    __shared__ float sS1[DD];
    __shared__ float sw2[DD * AA];
    __shared__ float sb1[DD];
    __shared__ float sb2[AA];
    for (int i = threadIdx.x; i < 192 * DD; i += 256) sw1[i] = w1[i];
    for (int i = threadIdx.x; i < DD * AA; i += 256) sw2[i] = w2[i];
    if (threadIdx.x < DD) sb1[threadIdx.x] = b1[threadIdx.x];
    if (threadIdx.x < AA) sb2[threadIdx.x] = b2[threadIdx.x];
    __syncthreads();
    if (threadIdx.x < DD) {
        float s = 0.f;
        for (int c = 0; c < 64; ++c) s += sw1[(128 + c) * DD + threadIdx.x];
        sS1[threadIdx.x] = s;
    }
    __syncthreads();
    const int lane = threadIdx.x & 31;
    const int grp = (blockIdx.x * 256 + threadIdx.x) >> 5;  // 0..255
    const int t0 = grp * 32;
    const int t = t0 + lane;
    const int pidx = t0 >> 7;                                // 0..63
    const float poolv = (pidx < DD) ? g_q[pidx] : (g_part[1 + (pidx - DD)] / g_part[0]);
    const int col = (t0 >> 5) & 3;
    const int rowbase = t0 >> 7;
    float4 acc[8];
#pragma unroll
    for (int q = 0; q < 8; ++q) {
        acc[q].x = fmaf(poolv, sS1[4 * q + 0], sb1[4 * q + 0]);
        acc[q].y = fmaf(poolv, sS1[4 * q + 1], sb1[4 * q + 1]);
        acc[q].z = fmaf(poolv, sS1[4 * q + 2], sb1[4 * q + 2]);
        acc[q].w = fmaf(poolv, sS1[4 * q + 3], sb1[4 * q + 3]);
    }
    for (int p = 0; p < 128; ++p) {
        const int node = nr[(p * 64 + rowbase) * 4 + col];
        const float v = g_out[node * DD + lane];
#pragma unroll
        for (int q = 0; q < 8; ++q) fma4(acc[q], v, *(const float4*)&sw1[p * DD + 4 * q]);
    }
    float y[AA];
#pragma unroll
    for (int a = 0; a < AA; ++a) y[a] = sb2[a];
#pragma unroll
    for (int q = 0; q < 8; ++q) {
        const float vals[4] = {acc[q].x, acc[q].y, acc[q].z, acc[q].w};
#pragma unroll
        for (int c = 0; c < 4; ++c) {
            const float ad = fmaxf(vals[c], 0.f);
            const int d = 4 * q + c;
#pragma unroll
            for (int a = 0; a < AA; ++a) y[a] = fmaf(ad, sw2[d * AA + a], y[a]);
        }
    }
#pragma unroll
    for (int a = 0; a < AA; ++a) yout[t * AA + a] = y[a];
}

extern "C" void kernel_launch(void* const* d_in, const int* in_sizes, int n_in,
                              void* d_out, int out_size, void* d_ws, size_t ws_size,
                              hipStream_t stream) {
    (void)in_sizes; (void)n_in; (void)out_size; (void)d_ws; (void)ws_size;
    const float* x        = (const float*)d_in[0];
    const int*   ei       = (const int*)d_in[1];
    const float* ea       = (const float*)d_in[2];
    const int*   nonring  = (const int*)d_in[3];
    const float* lin0_w   = (const float*)d_in[4];
    const float* lin0_b   = (const float*)d_in[5];
    const float* nn1_w    = (const float*)d_in[6];
    const float* nn1_b    = (const float*)d_in[7];
    const float* nn2_w    = (const float*)d_in[8];
    const float* nn2_b    = (const float*)d_in[9];
    const float* conv_root= (const float*)d_in[10];
    const float* conv_b   = (const float*)d_in[11];
    const float* gru_w_ih = (const float*)d_in[12];
    const float* gru_w_hh = (const float*)d_in[13];
    const float* gru_b_ih = (const float*)d_in[14];
    const float* gru_b_hh = (const float*)d_in[15];
    const float* lstm_w_ih= (const float*)d_in[16];
    const float* lstm_w_hh= (const float*)d_in[17];
    const float* lstm_b_ih= (const float*)d_in[18];
    const float* lstm_b_hh= (const float*)d_in[19];
    const float* lin1_w   = (const float*)d_in[20];
    const float* lin1_b   = (const float*)d_in[21];
    const float* lin2_w   = (const float*)d_in[22];
    const float* lin2_b   = (const float*)d_in[23];
    float* out = (float*)d_out;

    k_init<<<(NN * DD) / 256, 256, 0, stream>>>(x, lin0_w, lin0_b);
    k_deg<<<NE / 256, 256, 0, stream>>>(ei);
    k_h2<<<(NE * DD) / 256, 256, 0, stream>>>(ea, nn1_w, nn1_b);
    k_w2frag<<<132, 256, 0, stream>>>(nn2_w, nn2_b);
    for (int it = 0; it < 6; ++it) {
        k_edge_mfma<<<NE / 16 / 8, 512, 0, stream>>>(ei);
        k_node<<<(NN + 255) / 256, 256, 0, stream>>>(conv_root, conv_b, gru_w_ih, gru_w_hh,
                                                     gru_b_ih, gru_b_hh);
    }
    for (int s = 0; s < 6; ++s) {
        k_lstm<<<1, 128, 0, stream>>>(lstm_w_ih, lstm_w_hh, lstm_b_ih, lstm_b_hh, s);
        k_att<<<128, 256, 0, stream>>>();
    }
    k_readout<<<32, 256, 0, stream>>>(nonring, lin1_w, lin1_b, lin2_w, lin2_b, out);
}

// Round 3
// 530.968 us; speedup vs baseline: 2.4402x; 1.3605x over previous
//
#include <hip/hip_runtime.h>
#include <hip/hip_bf16.h>

#define NN 50000
#define NE 160000
#define NT 8192
#define DD 32
#define AA 6

typedef __attribute__((ext_vector_type(8))) short bf16x8s;
typedef __attribute__((ext_vector_type(4))) float f32x4;

// ---- static device scratch ----
__device__ float g_out[NN * DD];          // node features / GRU hidden (6.4 MB)
__device__ float g_agg[NN * DD];          // scatter accumulator (6.4 MB)
__device__ float g_invdeg[NN];            // raw in-degree count
__device__ float g_h2[NE * DD];           // relu(edge_attr@nn1_w+b) (20.5 MB)
__device__ bf16x8s g_w2frag[33 * 2 * 64]; // prepacked W2 B-frags (66 KB)
__device__ bf16x8s g_gru_frag[28 * 64];   // prepacked GRU B-frags hi/lo (28 KB)
__device__ float g_hl[DD], g_cl[DD], g_q[DD], g_part[DD + 1];
__device__ unsigned int g_cnt;            // zero at module load; reset after each use

__device__ __forceinline__ float sigm(float x) { return 1.0f / (1.0f + __expf(-x)); }
__device__ __forceinline__ float tanhx(float x) { return 1.0f - 2.0f / (__expf(2.0f * x) + 1.0f); }
__device__ __forceinline__ unsigned short f2bf(float f) {
    unsigned int u = __float_as_uint(f);
    u = (u + 0x7fffu + ((u >> 16) & 1u)) >> 16;
    return (unsigned short)u;
}
__device__ __forceinline__ float bflo(unsigned int pk) { return __uint_as_float(pk << 16); }
__device__ __forceinline__ float bfhi(unsigned int pk) { return __uint_as_float(pk & 0xffff0000u); }
__device__ __forceinline__ void fma4(float4& a, float s, const float4 b) {
    a.x = fmaf(s, b.x, a.x); a.y = fmaf(s, b.y, a.y);
    a.z = fmaf(s, b.z, a.z); a.w = fmaf(s, b.w, a.w);
}
#define CVTPK(dst, lo, hi) asm("v_cvt_pk_bf16_f32 %0, %1, %2" : "=v"(dst) : "v"(lo), "v"(hi))

// split f32[8] into bf16 hi + bf16 residual-lo fragments (f32-equivalent via 3 MFMAs)
__device__ __forceinline__ void split8(const float* v, bf16x8s& hi, bf16x8s& lo) {
    union U { bf16x8s v; unsigned int u[4]; } H, L;
    CVTPK(H.u[0], v[0], v[1]); CVTPK(H.u[1], v[2], v[3]);
    CVTPK(H.u[2], v[4], v[5]); CVTPK(H.u[3], v[6], v[7]);
    float r[8];
#pragma unroll
    for (int q = 0; q < 4; ++q) {
        r[2 * q]     = v[2 * q]     - bflo(H.u[q]);
        r[2 * q + 1] = v[2 * q + 1] - bfhi(H.u[q]);
    }
    CVTPK(L.u[0], r[0], r[1]); CVTPK(L.u[1], r[2], r[3]);
    CVTPK(L.u[2], r[4], r[5]); CVTPK(L.u[3], r[6], r[7]);
    hi = H.v; lo = L.v;
}

// out = relu(x @ lin0_w + lin0_b); zero agg; zero deg counter
__global__ __launch_bounds__(256) void k_init(const float* __restrict__ x,
                                              const float* __restrict__ w,
                                              const float* __restrict__ b) {
    const int t = blockIdx.x * 256 + threadIdx.x;   // exact N*32
    const int n = t >> 5, d = t & 31;
    float v = b[d];
    v = fmaf(x[n * 3 + 0], w[0 * DD + d], v);
    v = fmaf(x[n * 3 + 1], w[1 * DD + d], v);
    v = fmaf(x[n * 3 + 2], w[2 * DD + d], v);
    g_out[t] = fmaxf(v, 0.f);
    g_agg[t] = 0.f;
    if (d == 0) g_invdeg[n] = 0.f;
}

__global__ __launch_bounds__(256) void k_deg(const int* __restrict__ ei) {
    const int e = blockIdx.x * 256 + threadIdx.x;   // exact E
    atomicAdd(&g_invdeg[ei[NE + e]], 1.0f);
}

// h2 = relu(edge_attr @ nn1_w + nn1_b)
__global__ __launch_bounds__(256) void k_h2(const float* __restrict__ ea,
                                            const float* __restrict__ w,
                                            const float* __restrict__ b) {
    const int t = blockIdx.x * 256 + threadIdx.x;   // exact E*32
    const int e = t >> 5, k = t & 31;
    float acc = b[k];
#pragma unroll
    for (int i = 0; i < 7; ++i) acc = fmaf(ea[e * 7 + i], w[i * DD + k], acc);
    g_h2[t] = fmaxf(acc, 0.f);
}

// Prepack W2' B fragments (validated layout): frag[s][c][lane][j] = W2'[32s+8*(lane>>4)+j][c*16+(lane&15)]
__global__ __launch_bounds__(256) void k_w2frag(const float* __restrict__ w2m,
                                                const float* __restrict__ b2m) {
    const int idx = blockIdx.x * 256 + threadIdx.x;  // exact 33*2*64*8 = 33792
    const int j = idx & 7, l = (idx >> 3) & 63, c = (idx >> 9) & 1, s = idx >> 10;
    const int kk = (l >> 4) * 8 + j;
    const int col = c * 16 + (l & 15);
    const float v = (s == 32) ? b2m[kk * DD + col] : w2m[(32 * s + kk) * DD + col];
    ((unsigned short*)g_w2frag)[idx] = f2bf(v);
}

// Prepack GRU/root B-frags, hi + residual-lo parts.
// f: 0..3 root(c,part), 4..15 wih(c,part), 16..27 whh(c,part)
__global__ __launch_bounds__(256) void k_gfrag(const float* __restrict__ root,
                                               const float* __restrict__ wih,
                                               const float* __restrict__ whh) {
    const int tid = blockIdx.x * 256 + threadIdx.x;
    if (tid >= 28 * 64) return;
    const int lane = tid & 63, f = tid >> 6;
    const float* M; int ncols, c, part;
    if (f < 4)       { M = root; ncols = 32; c = f >> 1;        part = f & 1; }
    else if (f < 16) { M = wih;  ncols = 96; c = (f - 4) >> 1;  part = f & 1; }
    else             { M = whh;  ncols = 96; c = (f - 16) >> 1; part = f & 1; }
    unsigned short out8[8];
#pragma unroll
    for (int j = 0; j < 8; ++j) {
        const int k = (lane >> 4) * 8 + j;
        const float v = M[k * ncols + c * 16 + (lane & 15)];
        const unsigned short hi = f2bf(v);
        out8[j] = (part == 0) ? hi : f2bf(v - __uint_as_float((unsigned int)hi << 16));
    }
    g_gru_frag[f * 64 + lane] = *(bf16x8s*)out8;
}

// Fused NNConv edge pass via MFMA: msg = z @ W2' with z = h2 (x) u built in registers.
__global__ __launch_bounds__(512) void k_edge_mfma(const int* __restrict__ ei) {
    __shared__ bf16x8s sB[33 * 2 * 64];   // 66 KB
    for (int i = threadIdx.x; i < 33 * 2 * 64; i += 512)
        ((uint4*)sB)[i] = ((const uint4*)g_w2frag)[i];
    __syncthreads();

    const int wid = threadIdx.x >> 6, lane = threadIdx.x & 63;
    const int g = blockIdx.x * 8 + wid;              // 1250*8 = 10000 = NE/16
    const int e0 = g * 16;
    const int egrp = lane & 15;
    const int quad = lane >> 4;
    const int e = e0 + egrp;
    const int src = ei[e];

    const float4 u0 = *(const float4*)&g_out[src * DD + quad * 8];
    const float4 u1 = *(const float4*)&g_out[src * DD + quad * 8 + 4];
    float h2r[DD];
#pragma unroll
    for (int q = 0; q < 8; ++q)
        *(float4*)&h2r[4 * q] = *(const float4*)&g_h2[(size_t)e * DD + 4 * q];

    union ABu { bf16x8s v; unsigned int u[4]; };
    ABu Au;
    CVTPK(Au.u[0], u0.x, u0.y); CVTPK(Au.u[1], u0.z, u0.w);
    CVTPK(Au.u[2], u1.x, u1.y); CVTPK(Au.u[3], u1.z, u1.w);

    f32x4 acc0 = {0.f, 0.f, 0.f, 0.f};
    f32x4 acc1 = {0.f, 0.f, 0.f, 0.f};
#pragma unroll
    for (int s = 0; s < DD; ++s) {
        const float hs = h2r[s];
        ABu A;
        CVTPK(A.u[0], hs * u0.x, hs * u0.y);
        CVTPK(A.u[1], hs * u0.z, hs * u0.w);
        CVTPK(A.u[2], hs * u1.x, hs * u1.y);
        CVTPK(A.u[3], hs * u1.z, hs * u1.w);
        const bf16x8s b0 = sB[s * 128 + lane];
        const bf16x8s b1 = sB[s * 128 + 64 + lane];
        acc0 = __builtin_amdgcn_mfma_f32_16x16x32_bf16(A.v, b0, acc0, 0, 0, 0);
        acc1 = __builtin_amdgcn_mfma_f32_16x16x32_bf16(A.v, b1, acc1, 0, 0, 0);
    }
    {
        const bf16x8s b0 = sB[32 * 128 + lane];
        const bf16x8s b1 = sB[32 * 128 + 64 + lane];
        acc0 = __builtin_amdgcn_mfma_f32_16x16x32_bf16(Au.v, b0, acc0, 0, 0, 0);
        acc1 = __builtin_amdgcn_mfma_f32_16x16x32_bf16(Au.v, b1, acc1, 0, 0, 0);
    }
    const int oc = lane & 15;
#pragma unroll
    for (int r = 0; r < 4; ++r) {
        const int dstn = ei[NE + e0 + quad * 4 + r];
        atomicAdd(&g_agg[dstn * DD + oc], acc0[r]);
        atomicAdd(&g_agg[dstn * DD + 16 + oc], acc1[r]);
    }
}

// GRU node update via MFMA (split-bf16, f32-equivalent). One wave = 16 nodes.
__global__ __launch_bounds__(256) void k_node_mfma(const float* __restrict__ cb,
                                                   const float* __restrict__ bih,
                                                   const float* __restrict__ bhh) {
    __shared__ float sm[4][16 * 36];      // wave-private m-transpose tile (pad 36)
    const int wid = threadIdx.x >> 6, lane = threadIdx.x & 63;
    const int nt = blockIdx.x * 4 + wid;
    if (nt >= NN / 16) return;            // 3125 tiles exactly
    const int nb = nt * 16;
    const int col = lane & 15, quad = lane >> 4;
    const bf16x8s* FB = g_gru_frag;

    // h A-frag (row = lane&15 node, k = quad*8+j), split hi/lo
    float hv8[8];
    *(float4*)&hv8[0] = *(const float4*)&g_out[(nb + col) * DD + quad * 8];
    *(float4*)&hv8[4] = *(const float4*)&g_out[(nb + col) * DD + quad * 8 + 4];
    bf16x8s hAh, hAl; split8(hv8, hAh, hAl);

    float invr[4];
#pragma unroll
    for (int r = 0; r < 4; ++r) invr[r] = 1.0f / fmaxf(g_invdeg[nb + quad * 4 + r], 1.0f);

    // m = relu(h@root + agg*inv + cb), D-layout (row = quad*4+r, col)
#pragma unroll
    for (int c = 0; c < 2; ++c) {
        const float cbv = cb[c * 16 + col];
        f32x4 aM;
#pragma unroll
        for (int r = 0; r < 4; ++r)
            aM[r] = fmaf(g_agg[(nb + quad * 4 + r) * DD + c * 16 + col], invr[r], cbv);
        const bf16x8s Bh = FB[(c * 2 + 0) * 64 + lane];
        const bf16x8s Bl = FB[(c * 2 + 1) * 64 + lane];
        aM = __builtin_amdgcn_mfma_f32_16x16x32_bf16(hAh, Bh, aM, 0, 0, 0);
        aM = __builtin_amdgcn_mfma_f32_16x16x32_bf16(hAl, Bh, aM, 0, 0, 0);
        aM = __builtin_amdgcn_mfma_f32_16x16x32_bf16(hAh, Bl, aM, 0, 0, 0);
#pragma unroll
        for (int r = 0; r < 4; ++r)
            sm[wid][(quad * 4 + r) * 36 + c * 16 + col] = fmaxf(aM[r], 0.f);
    }

    // read m back as A-frag (wave-private LDS; compiler orders ds ops)
    float mv8[8];
    *(float4*)&mv8[0] = *(const float4*)&sm[wid][col * 36 + quad * 8];
    *(float4*)&mv8[4] = *(const float4*)&sm[wid][col * 36 + quad * 8 + 4];
    bf16x8s mAh, mAl; split8(mv8, mAh, mAl);

    f32x4 R[2], Z[2], XN[2], HN[2];
#pragma unroll
    for (int c = 0; c < 6; ++c) {
        const float bx = bih[c * 16 + col], bh = bhh[c * 16 + col];
        f32x4 aX = {bx, bx, bx, bx}, aH = {bh, bh, bh, bh};
        const bf16x8s WIhf = FB[(4 + c * 2) * 64 + lane];
        const bf16x8s WIlf = FB[(5 + c * 2) * 64 + lane];
        const bf16x8s WHhf = FB[(16 + c * 2) * 64 + lane];
        const bf16x8s WHlf = FB[(17 + c * 2) * 64 + lane];
        aX = __builtin_amdgcn_mfma_f32_16x16x32_bf16(mAh, WIhf, aX, 0, 0, 0);
        aX = __builtin_amdgcn_mfma_f32_16x16x32_bf16(mAl, WIhf, aX, 0, 0, 0);
        aX = __builtin_amdgcn_mfma_f32_16x16x32_bf16(mAh, WIlf, aX, 0, 0, 0);
        aH = __builtin_amdgcn_mfma_f32_16x16x32_bf16(hAh, WHhf, aH, 0, 0, 0);
        aH = __builtin_amdgcn_mfma_f32_16x16x32_bf16(hAl, WHhf, aH, 0, 0, 0);
        aH = __builtin_amdgcn_mfma_f32_16x16x32_bf16(hAh, WHlf, aH, 0, 0, 0);
        if (c < 2) {
#pragma unroll
            for (int r = 0; r < 4; ++r) R[c][r] = sigm(aX[r] + aH[r]);
        } else if (c < 4) {
#pragma unroll
            for (int r = 0; r < 4; ++r) Z[c - 2][r] = sigm(aX[r] + aH[r]);
        } else {
            XN[c - 4] = aX; HN[c - 4] = aH;
        }
    }
#pragma unroll
    for (int c = 0; c < 2; ++c)
#pragma unroll
        for (int r = 0; r < 4; ++r) {
            const int addr = (nb + quad * 4 + r) * DD + c * 16 + col;
            const float nv = tanhx(XN[c][r] + R[c][r] * HN[c][r]);
            const float hv = g_out[addr];
            g_out[addr] = (1.f - Z[c][r]) * nv + Z[c][r] * hv;
            g_agg[addr] = 0.f;
        }
}

// Set2Set step 0: LSTM with zero inputs (gates = biases only); init g_part/g_cnt.
__global__ void k_lstm0(const float* __restrict__ bih, const float* __restrict__ bhh) {
    __shared__ float gg[128];
    const int t = threadIdx.x;  // 128
    gg[t] = bih[t] + bhh[t];
    __syncthreads();
    if (t < DD) {
        const float ig = sigm(gg[t]), fg = sigm(gg[DD + t]);
        const float g2 = tanhx(gg[2 * DD + t]), og = sigm(gg[3 * DD + t]);
        const float cc = ig * g2;
        g_cl[t] = cc; const float hn = og * tanhx(cc); g_hl[t] = hn; g_q[t] = hn;
        (void)fg;
    }
    if (t >= DD && t < 2 * DD + 1) g_part[t - DD] = 0.f;
    if (t == 0) g_cnt = 0u;
}

// attention pass + (last block) fused LSTM step for the next iteration
__global__ __launch_bounds__(256) void k_att_f(const float* __restrict__ wih,
                                               const float* __restrict__ whh,
                                               const float* __restrict__ bih,
                                               const float* __restrict__ bhh,
                                               const int dolstm) {
    __shared__ float sq[DD];
    __shared__ float red[4][DD + 1];
    __shared__ int slast;
    __shared__ float qs[64], shl[DD], gg[128];
    if (threadIdx.x < DD) sq[threadIdx.x] = g_q[threadIdx.x];
    __syncthreads();
    float pe = 0.f;
    float pv[DD];
#pragma unroll
    for (int i = 0; i < DD; ++i) pv[i] = 0.f;
    for (int n = blockIdx.x * blockDim.x + threadIdx.x; n < NN; n += gridDim.x * blockDim.x) {
        float row[DD];
#pragma unroll
        for (int q = 0; q < 8; ++q) *(float4*)&row[4 * q] = *(const float4*)&g_out[n * DD + 4 * q];
        float dot = 0.f;
#pragma unroll
        for (int i = 0; i < DD; ++i) dot = fmaf(row[i], sq[i], dot);
        const float e = __expf(dot);
        pe += e;
#pragma unroll
        for (int i = 0; i < DD; ++i) pv[i] = fmaf(e, row[i], pv[i]);
    }
#pragma unroll
    for (int off = 32; off > 0; off >>= 1) {
        pe += __shfl_down(pe, off, 64);
#pragma unroll
        for (int i = 0; i < DD; ++i) pv[i] += __shfl_down(pv[i], off, 64);
    }
    const int wid = threadIdx.x >> 6, lane = threadIdx.x & 63;
    if (lane == 0) {
        red[wid][0] = pe;
#pragma unroll
        for (int i = 0; i < DD; ++i) red[wid][1 + i] = pv[i];
    }
    __syncthreads();
    if (threadIdx.x < DD + 1) {
        const float s = red[0][threadIdx.x] + red[1][threadIdx.x] + red[2][threadIdx.x] + red[3][threadIdx.x];
        atomicAdd(&g_part[threadIdx.x], s);
    }
    // completion-counter: last block to finish performs the next LSTM step
    __threadfence();
    __syncthreads();
    if (threadIdx.x == 0) {
        const unsigned int o = atomicAdd(&g_cnt, 1u);
        slast = (o == (unsigned int)(gridDim.x - 1)) ? 1 : 0;
    }
    __syncthreads();
    if (!slast) return;
    __threadfence();
    const int t = threadIdx.x;
    if (dolstm) {
        if (t < DD) { qs[t] = g_q[t]; shl[t] = g_hl[t]; }
        else if (t < 64) qs[t] = g_part[1 + t - DD] / g_part[0];
        __syncthreads();
        if (t < 128) {
            float acc = bih[t] + bhh[t];
            for (int i = 0; i < 64; ++i) acc = fmaf(qs[i], wih[i * 128 + t], acc);
            for (int i = 0; i < DD; ++i) acc = fmaf(shl[i], whh[i * 128 + t], acc);
            gg[t] = acc;
        }
        __syncthreads();
        if (t < DD) {
            const float ig = sigm(gg[t]), fg = sigm(gg[DD + t]);
            const float g2 = tanhx(gg[2 * DD + t]), og = sigm(gg[3 * DD + t]);
            const float cc = fmaf(fg, g_cl[t], ig * g2);
            g_cl[t] = cc; const float hn = og * tanhx(cc); g_hl[t] = hn; g_q[t] = hn;
        }
        if (t >= DD && t < 2 * DD + 1) g_part[t - DD] = 0.f;
    }
    if (t == 0) g_cnt = 0u;
}

// readout: 256 blocks x 128 threads, p-loop split 4-way across lane-slices
__global__ __launch_bounds__(128) void k_readout(const int* __restrict__ nr,
                                                 const float* __restrict__ w1,
                                                 const float* __restrict__ b1,
                                                 const float* __restrict__ w2,
                                                 const float* __restrict__ b2,
                                                 float* __restrict__ yout) {
    __shared__ float sw1[192 * DD];
    __shared__ float sS1[DD];
    __shared__ float sw2[DD * AA];
    __shared__ float sb1[DD];
    __shared__ float sb2[AA];
    __shared__ float sred[32 * DD];
    for (int i = threadIdx.x; i < 192 * DD; i += 128) sw1[i] = w1[i];
    for (int i = threadIdx.x; i < DD * AA; i += 128) sw2[i] = w2[i];
    if (threadIdx.x < DD) sb1[threadIdx.x] = b1[threadIdx.x];
    if (threadIdx.x >= DD && threadIdx.x < DD + AA) sb2[threadIdx.x - DD] = b2[threadIdx.x - DD];
    __syncthreads();
    if (threadIdx.x < DD) {
        float s = 0.f;
        for (int c = 0; c < 64; ++c) s += sw1[(128 + c) * DD + threadIdx.x];
        sS1[threadIdx.x] = s;
    }
    __syncthreads();
    const int g = blockIdx.x;            // t-group 0..255
    const int t0 = g * 32;
    const int f = threadIdx.x & 31;      // t-offset == feature index
    const int slice = threadIdx.x >> 5;  // 0..3 p-slices
    const int rowbase = g >> 2, col = g & 3;
    float4 acc[8];
#pragma unroll
    for (int q = 0; q < 8; ++q) acc[q] = make_float4(0.f, 0.f, 0.f, 0.f);
    for (int pp = 0; pp < 32; ++pp) {
        const int p = slice * 32 + pp;
        const int node = nr[(p * 64 + rowbase) * 4 + col];
        const float v = g_out[node * DD + f];
#pragma unroll
        for (int q = 0; q < 8; ++q) fma4(acc[q], v, *(const float4*)&sw1[p * DD + 4 * q]);
    }
#pragma unroll
    for (int q = 0; q < 8; ++q) {
        acc[q].x += __shfl_xor(acc[q].x, 32, 64);
        acc[q].y += __shfl_xor(acc[q].y, 32, 64);
        acc[q].z += __shfl_xor(acc[q].z, 32, 64);
        acc[q].w += __shfl_xor(acc[q].w, 32, 64);
    }
    if (threadIdx.x >= 64 && threadIdx.x < 96) {
#pragma unroll
        for (int q = 0; q < 8; ++q) *(float4*)&sred[f * DD + 4 * q] = acc[q];
    }
    __syncthreads();
    if (threadIdx.x < 32) {
        const int pidx = g >> 2;
        const float poolv = (pidx < DD) ? g_q[pidx] : (g_part[1 + (pidx - DD)] / g_part[0]);
        float y[AA];
#pragma unroll
        for (int a = 0; a < AA; ++a) y[a] = sb2[a];
#pragma unroll
        for (int q = 0; q < 8; ++q) {
            const float4 o = *(const float4*)&sred[f * DD + 4 * q];
            const float vals[4] = {acc[q].x + o.x, acc[q].y + o.y, acc[q].z + o.z, acc[q].w + o.w};
#pragma unroll
            for (int cc = 0; cc < 4; ++cc) {
                const int d = 4 * q + cc;
                const float ad = fmaxf(fmaf(poolv, sS1[d], sb1[d]) + vals[cc], 0.f);
#pragma unroll
                for (int a = 0; a < AA; ++a) y[a] = fmaf(ad, sw2[d * AA + a], y[a]);
            }
        }
#pragma unroll
        for (int a = 0; a < AA; ++a) yout[(t0 + f) * AA + a] = y[a];
    }
}

extern "C" void kernel_launch(void* const* d_in, const int* in_sizes, int n_in,
                              void* d_out, int out_size, void* d_ws, size_t ws_size,
                              hipStream_t stream) {
    (void)in_sizes; (void)n_in; (void)out_size; (void)d_ws; (void)ws_size;
    const float* x        = (const float*)d_in[0];
    const int*   ei       = (const int*)d_in[1];
    const float* ea       = (const float*)d_in[2];
    const int*   nonring  = (const int*)d_in[3];
    const float* lin0_w   = (const float*)d_in[4];
    const float* lin0_b   = (const float*)d_in[5];
    const float* nn1_w    = (const float*)d_in[6];
    const float* nn1_b    = (const float*)d_in[7];
    const float* nn2_w    = (const float*)d_in[8];
    const float* nn2_b    = (const float*)d_in[9];
    const float* conv_root= (const float*)d_in[10];
    const float* conv_b   = (const float*)d_in[11];
    const float* gru_w_ih = (const float*)d_in[12];
    const float* gru_w_hh = (const float*)d_in[13];
    const float* gru_b_ih = (const float*)d_in[14];
    const float* gru_b_hh = (const float*)d_in[15];
    const float* lstm_w_ih= (const float*)d_in[16];
    const float* lstm_w_hh= (const float*)d_in[17];
    const float* lstm_b_ih= (const float*)d_in[18];
    const float* lstm_b_hh= (const float*)d_in[19];
    const float* lin1_w   = (const float*)d_in[20];
    const float* lin1_b   = (const float*)d_in[21];
    const float* lin2_w   = (const float*)d_in[22];
    const float* lin2_b   = (const float*)d_in[23];
    float* out = (float*)d_out;

    k_init<<<(NN * DD) / 256, 256, 0, stream>>>(x, lin0_w, lin0_b);
    k_deg<<<NE / 256, 256, 0, stream>>>(ei);
    k_h2<<<(NE * DD) / 256, 256, 0, stream>>>(ea, nn1_w, nn1_b);
    k_w2frag<<<132, 256, 0, stream>>>(nn2_w, nn2_b);
    k_gfrag<<<7, 256, 0, stream>>>(conv_root, gru_w_ih, gru_w_hh);
    for (int it = 0; it < 6; ++it) {
        k_edge_mfma<<<NE / 16 / 8, 512, 0, stream>>>(ei);
        k_node_mfma<<<(NN / 16 + 3) / 4, 256, 0, stream>>>(conv_b, gru_b_ih, gru_b_hh);
    }
    k_lstm0<<<1, 128, 0, stream>>>(lstm_b_ih, lstm_b_hh);
    for (int s = 0; s < 6; ++s) {
        k_att_f<<<196, 256, 0, stream>>>(lstm_w_ih, lstm_w_hh, lstm_b_ih, lstm_b_hh, (s < 5) ? 1 : 0);
    }
    k_readout<<<256, 128, 0, stream>>>(nonring, lin1_w, lin1_b, lin2_w, lin2_b, out);
}